// Round 5
// baseline (85.157 us; speedup 1.0000x reference)
//
#include <hip/hip_runtime.h>
#include <math.h>

#define TANFOV 1.0f

// AoS gaussian record: 3 x float4
//   [0] = (tz, -0.5*conA, -conB, -0.5*conC)
//   [1] = (mx, my, op(0 if invalid), 0)
//   [2] = (c0, c1, c2, 0)
#define REC 12      // floats per gaussian
#define CHG 256     // gaussians per chunk (== blend1 block size)

// ---------------------------------------------------------------------------
// Kernel 1: per-gaussian preprocessing. frest staged through LDS so the
// stride-45 access becomes coalesced. Writes AoS record + conservative
// support bbox (x0,x1,y0,y1) + tz array + radii (to output).
// ---------------------------------------------------------------------------
#define PRE_TB 256

__global__ void preprocess_kernel(
    const float* __restrict__ xyz, const float* __restrict__ scaling,
    const float* __restrict__ rotation, const float* __restrict__ opacity,
    const float* __restrict__ fdc, const float* __restrict__ frest,
    const float* __restrict__ vm, const float* __restrict__ pm,
    const float* __restrict__ campos,
    const int* __restrict__ pH, const int* __restrict__ pW,
    float* __restrict__ pre, float4* __restrict__ bboxpre,
    float* __restrict__ tzarr, float* __restrict__ radii_out, int N)
{
    __shared__ float s_fr[PRE_TB * 45];
    int i0 = blockIdx.x * PRE_TB;
    int cnt = N - i0; if (cnt > PRE_TB) cnt = PRE_TB;
    for (int t = threadIdx.x; t < cnt * 45; t += PRE_TB)
        s_fr[t] = frest[(size_t)i0 * 45 + t];
    __syncthreads();

    int i = i0 + threadIdx.x;
    if (i >= N) return;
    float H = (float)*pH, W = (float)*pW;

    float px_ = xyz[i*3+0], py_ = xyz[i*3+1], pz_ = xyz[i*3+2];
    float s0 = expf(scaling[i*3+0]), s1 = expf(scaling[i*3+1]), s2 = expf(scaling[i*3+2]);
    float op = 1.f / (1.f + expf(-opacity[i]));

    float qw = rotation[i*4+0], qx = rotation[i*4+1], qy = rotation[i*4+2], qz = rotation[i*4+3];
    float qn = fmaxf(sqrtf(qw*qw + qx*qx + qy*qy + qz*qz), 1e-12f);
    qw /= qn; qx /= qn; qy /= qn; qz /= qn;

    float R00 = 1.f - 2.f*(qy*qy + qz*qz), R01 = 2.f*(qx*qy - qw*qz), R02 = 2.f*(qx*qz + qw*qy);
    float R10 = 2.f*(qx*qy + qw*qz), R11 = 1.f - 2.f*(qx*qx + qz*qz), R12 = 2.f*(qy*qz - qw*qx);
    float R20 = 2.f*(qx*qz - qw*qy), R21 = 2.f*(qy*qz + qw*qx), R22 = 1.f - 2.f*(qx*qx + qy*qy);

    float M00 = R00*s0, M01 = R01*s1, M02 = R02*s2;
    float M10 = R10*s0, M11 = R11*s1, M12 = R12*s2;
    float M20 = R20*s0, M21 = R21*s1, M22 = R22*s2;

    float S00 = M00*M00 + M01*M01 + M02*M02;
    float S01 = M00*M10 + M01*M11 + M02*M12;
    float S02 = M00*M20 + M01*M21 + M02*M22;
    float S11 = M10*M10 + M11*M11 + M12*M12;
    float S12 = M10*M20 + M11*M21 + M12*M22;
    float S22 = M20*M20 + M21*M21 + M22*M22;

    float t0 = px_*vm[0] + py_*vm[4] + pz_*vm[8]  + vm[12];
    float t1 = px_*vm[1] + py_*vm[5] + pz_*vm[9]  + vm[13];
    float tz = px_*vm[2] + py_*vm[6] + pz_*vm[10] + vm[14];

    float fx = W / (2.f * TANFOV), fy = H / (2.f * TANFOV);
    float lim = 1.3f * TANFOV;
    float tzs = (fabsf(tz) > 1e-6f) ? tz : 1e-6f;
    float txz = fminf(fmaxf(t0 / tzs, -lim), lim) * tzs;
    float tyz = fminf(fmaxf(t1 / tzs, -lim), lim) * tzs;
    float J00 = fx / tzs, J02 = -fx * txz / (tzs * tzs);
    float J11 = fy / tzs, J12 = -fy * tyz / (tzs * tzs);

    float T00 = J00*vm[0] + J02*vm[2];
    float T01 = J00*vm[4] + J02*vm[6];
    float T02 = J00*vm[8] + J02*vm[10];
    float T10 = J11*vm[1] + J12*vm[2];
    float T11 = J11*vm[5] + J12*vm[6];
    float T12 = J11*vm[9] + J12*vm[10];

    float u0 = S00*T00 + S01*T01 + S02*T02;
    float u1 = S01*T00 + S11*T01 + S12*T02;
    float u2 = S02*T00 + S12*T01 + S22*T02;
    float v0 = S00*T10 + S01*T11 + S02*T12;
    float v1 = S01*T10 + S11*T11 + S12*T12;
    float v2 = S02*T10 + S12*T11 + S22*T12;
    float a  = T00*u0 + T01*u1 + T02*u2 + 0.3f;
    float b  = T10*u0 + T11*u1 + T12*u2;
    float c  = T10*v0 + T11*v1 + T12*v2 + 0.3f;

    float det = a*c - b*b;
    bool valid = (tz > 0.2f) && (det > 0.f);
    float inv_det = 1.f / ((det > 0.f) ? det : 1.f);
    float conA = c * inv_det, conB = -b * inv_det, conC = a * inv_det;
    float mid = 0.5f * (a + c);
    float lam = mid + sqrtf(fmaxf(mid*mid - det, 0.1f));
    radii_out[i] = valid ? ceilf(3.f * sqrtf(lam)) : 0.f;

    float h0 = px_*pm[0] + py_*pm[4] + pz_*pm[8]  + pm[12];
    float h1 = px_*pm[1] + py_*pm[5] + pz_*pm[9]  + pm[13];
    float h3 = px_*pm[3] + py_*pm[7] + pz_*pm[11] + pm[15];
    float pw = 1.f / (h3 + 1e-7f);
    float mx = ((h0*pw + 1.f) * W - 1.f) * 0.5f;
    float my = ((h1*pw + 1.f) * H - 1.f) * 0.5f;

    float ddx = px_ - campos[0], ddy = py_ - campos[1], ddz = pz_ - campos[2];
    float dn = fmaxf(sqrtf(ddx*ddx + ddy*ddy + ddz*ddz), 1e-12f);
    float x = ddx/dn, y = ddy/dn, z = ddz/dn;
    float xx = x*x, yy = y*y, zz = z*z, xy = x*y, yz = y*z, xz = x*z;

    float basis[16];
    basis[0]  = 0.28209479177387814f;
    basis[1]  = -0.4886025119029199f * y;
    basis[2]  =  0.4886025119029199f * z;
    basis[3]  = -0.4886025119029199f * x;
    basis[4]  =  1.0925484305920792f * xy;
    basis[5]  = -1.0925484305920792f * yz;
    basis[6]  =  0.31539156525252005f * (2.f*zz - xx - yy);
    basis[7]  = -1.0925484305920792f * xz;
    basis[8]  =  0.5462742152960396f * (xx - yy);
    basis[9]  = -0.5900435899266435f * y * (3.f*xx - yy);
    basis[10] =  2.890611442640554f  * xy * z;
    basis[11] = -0.4570457994644658f * y * (4.f*zz - xx - yy);
    basis[12] =  0.3731763325901154f * z * (2.f*zz - 3.f*xx - 3.f*yy);
    basis[13] = -0.4570457994644658f * x * (4.f*zz - xx - yy);
    basis[14] =  1.445305721320277f  * z * (xx - yy);
    basis[15] = -0.5900435899266435f * x * (xx - 3.f*yy);

    const float* fr = &s_fr[threadIdx.x * 45];
    float col[3];
    #pragma unroll
    for (int ch = 0; ch < 3; ++ch) {
        float r = basis[0] * fdc[i*3 + ch];
        #pragma unroll
        for (int j = 1; j < 16; ++j)
            r += basis[j] * fr[(j-1)*3 + ch];
        col[ch] = fmaxf(r + 0.5f, 0.f);
    }

    float opv = valid ? op : 0.f;
    float4* rec = (float4*)(pre + (size_t)i * REC);
    rec[0] = make_float4(tz, -0.5f*conA, -conB, -0.5f*conC);
    rec[1] = make_float4(mx, my, opv, 0.f);
    rec[2] = make_float4(col[0], col[1], col[2], 0.f);

    float4 bb;
    if (opv > 1.f/255.f) {
        float Rr = 1.01f * sqrtf(2.f * logf(255.f * opv) * lam) + 1.f;
        bb = make_float4(mx - Rr, mx + Rr, my - Rr, my + Rr);
    } else {
        bb = make_float4(1e30f, -1e30f, 1e30f, -1e30f);   // empty
    }
    bboxpre[i] = bb;
    tzarr[i] = tz;
}

// ---------------------------------------------------------------------------
// Kernel 2: fused stable rank-sort + scatter. Whole tz array (N*4 B) staged
// in LDS; each thread computes the full rank of its gaussian and scatters
// record + bbox to sorted position.
// ---------------------------------------------------------------------------
__global__ void sort_kernel(const float* __restrict__ pre,
                            const float4* __restrict__ bboxpre,
                            const float* __restrict__ tzarr,
                            float* __restrict__ srt,
                            float4* __restrict__ bboxsrt, int N)
{
    extern __shared__ float s_tz[];
    for (int t = threadIdx.x; t < N; t += blockDim.x)
        s_tz[t] = tzarr[t];
    __syncthreads();

    int i = blockIdx.x * blockDim.x + threadIdx.x;
    if (i >= N) return;
    float key = s_tz[i];
    int rank = 0;
    #pragma unroll 4
    for (int j = 0; j < N; j += 4) {
        float4 v = *reinterpret_cast<float4*>(&s_tz[j]);
        rank += (v.x < key) || (v.x == key && (j)     < i);
        rank += (v.y < key) || (v.y == key && (j + 1) < i);
        rank += (v.z < key) || (v.z == key && (j + 2) < i);
        rank += (v.w < key) || (v.w == key && (j + 3) < i);
    }
    const float4* src = (const float4*)(pre + (size_t)i * REC);
    float4* dst = (float4*)(srt + (size_t)rank * REC);
    dst[0] = src[0]; dst[1] = src[1]; dst[2] = src[2];
    bboxsrt[rank] = bboxpre[i];
}

// ---------------------------------------------------------------------------
// Kernel 3: tile blend. Block = one 16x16 pixel tile x one 256-gaussian
// chunk (blockIdx.y). Phase A: each thread bbox-tests one gaussian against
// the tile (coalesced vector load), order-preserving ballot compaction into
// an LDS survivor list. Phase B: cooperative copy of survivor records to
// LDS, then per-pixel sequential blend over survivors (LDS broadcasts).
// part layout: field*(G*HW) + chunk*HW + pix; fields 0..2 color, 3 depth, 4 T
// Assumes W % 16 == 0 (true for this instance).
// ---------------------------------------------------------------------------
__global__ void blend1_kernel(const float4* __restrict__ grec,
                              const float4* __restrict__ bbox,
                              const int* __restrict__ pW,
                              float* __restrict__ part,
                              int N, int HW, int G)
{
    __shared__ int    s_cnt[4];
    __shared__ int    s_idx[CHG];
    __shared__ float4 s_rec[3 * CHG];

    int tid = threadIdx.x;
    int W = *pW;
    int tilesX = (W + 15) >> 4;
    int tileX = blockIdx.x % tilesX;
    int tileY = blockIdx.x / tilesX;
    int px = (tileX << 4) + (tid & 15);
    int py = (tileY << 4) + (tid >> 4);
    int pix = py * W + px;
    float fpx = (float)px, fpy = (float)py;
    float ftx0 = (float)(tileX << 4), ftx1 = ftx0 + 15.f;
    float fty0 = (float)(tileY << 4), fty1 = fty0 + 15.f;

    int chunk = blockIdx.y;
    int g0 = chunk * CHG;

    // ---- Phase A: cull ----
    int g = g0 + tid;
    bool hit = false;
    if (g < N) {
        float4 bb = bbox[g];                       // coalesced dwordx4
        hit = (bb.x <= ftx1) && (bb.y >= ftx0) &&
              (bb.z <= fty1) && (bb.w >= fty0);
    }
    unsigned long long m = __ballot(hit);
    int lane = tid & 63, wv = tid >> 6;
    int pos = __popcll(m & ((1ull << lane) - 1ull));
    if (lane == 0) s_cnt[wv] = __popcll(m);
    __syncthreads();
    int total = s_cnt[0] + s_cnt[1] + s_cnt[2] + s_cnt[3];
    int off = 0;
    for (int w = 0; w < wv; ++w) off += s_cnt[w];
    if (hit) s_idx[off + pos] = g;
    __syncthreads();

    // ---- Phase B: stage survivor records ----
    for (int k = tid; k < 3 * total; k += CHG) {
        int s = k / 3, e = k - 3 * s;
        s_rec[k] = grec[3 * s_idx[s] + e];
    }
    __syncthreads();

    // ---- blend over survivors (depth order preserved) ----
    float T = 1.f, c0 = 0.f, c1 = 0.f, c2 = 0.f, d = 0.f;
    for (int s = 0; s < total; ++s) {
        float4 pA = s_rec[3*s+0];   // tz, a2, b2, c2
        float4 pB = s_rec[3*s+1];   // mx, my, op, -
        float4 pC = s_rec[3*s+2];   // rgb
        float dx = fpx - pB.x, dy = fpy - pB.y;
        float power = pA.y*dx*dx + pA.w*dy*dy + pA.z*dx*dy;
        float alpha = fminf(0.99f, pB.z * __expf(fminf(power, 0.f)));
        bool keep = (power <= 0.f) && (alpha >= 1.f/255.f);
        float aeff = keep ? alpha : 0.f;
        float w = aeff * T;
        c0 = fmaf(w, pC.x, c0);
        c1 = fmaf(w, pC.y, c1);
        c2 = fmaf(w, pC.z, c2);
        d  = fmaf(w, pA.x, d);
        T  = T - aeff * T;
    }
    if (pix < HW) {
        int o = chunk * HW + pix;
        int S = G * HW;
        part[0*S+o] = c0; part[1*S+o] = c1; part[2*S+o] = c2;
        part[3*S+o] = d;  part[4*S+o] = T;
    }
}

// ---------------------------------------------------------------------------
// Kernel 4: combine chunks per pixel, write final outputs.
// out layout: color[3][HW], depth[HW], amap[HW]  (radii written by kernel 1)
// ---------------------------------------------------------------------------
__global__ void blend2_kernel(const float* __restrict__ part,
                              const float* __restrict__ bg,
                              float* __restrict__ out, int HW, int G)
{
    int pix = blockIdx.x * blockDim.x + threadIdx.x;
    if (pix >= HW) return;
    int S = G * HW;
    float T = 1.f, c0 = 0.f, c1 = 0.f, c2 = 0.f, d = 0.f;
    for (int k = 0; k < G; ++k) {
        int o = k * HW + pix;
        c0 += T * part[0*S+o];
        c1 += T * part[1*S+o];
        c2 += T * part[2*S+o];
        d  += T * part[3*S+o];
        T  *= part[4*S+o];
    }
    out[0*HW+pix] = c0 + T*bg[0];
    out[1*HW+pix] = c1 + T*bg[1];
    out[2*HW+pix] = c2 + T*bg[2];
    out[3*HW+pix] = d;
    out[4*HW+pix] = 1.f - T;
}

extern "C" void kernel_launch(void* const* d_in, const int* in_sizes, int n_in,
                              void* d_out, int out_size, void* d_ws, size_t ws_size,
                              hipStream_t stream) {
    const float* xyz      = (const float*)d_in[0];
    const float* scaling  = (const float*)d_in[1];
    const float* rotation = (const float*)d_in[2];
    const float* opacity  = (const float*)d_in[3];
    const float* fdc      = (const float*)d_in[4];
    const float* frest    = (const float*)d_in[5];
    const float* vm       = (const float*)d_in[6];
    const float* pm       = (const float*)d_in[7];
    const float* campos   = (const float*)d_in[8];
    const float* bg       = (const float*)d_in[9];
    const int*   pH       = (const int*)d_in[10];
    const int*   pW       = (const int*)d_in[11];

    int N  = in_sizes[0] / 3;
    int HW = (out_size - N) / 5;
    int G  = (N + CHG - 1) / CHG;     // 8 chunks for N=2048

    // ws layout (floats):
    //   pre     : REC*N
    //   srt     : REC*N
    //   bboxpre : 4*N
    //   bboxsrt : 4*N
    //   tzarr   : N
    //   part    : 5*G*HW
    float*  ws       = (float*)d_ws;
    float*  pre      = ws;
    float*  srt      = pre + (size_t)REC * N;
    float4* bboxpre  = (float4*)(srt + (size_t)REC * N);
    float4* bboxsrt  = bboxpre + N;
    float*  tzarr    = (float*)(bboxsrt + N);
    float*  part     = tzarr + N;

    float* out   = (float*)d_out;
    float* radii = out + (size_t)5 * HW;

    int tb = 256;
    preprocess_kernel<<<(N + PRE_TB - 1) / PRE_TB, PRE_TB, 0, stream>>>(
        xyz, scaling, rotation, opacity, fdc, frest, vm, pm, campos, pH, pW,
        pre, bboxpre, tzarr, radii, N);
    sort_kernel<<<(N + tb - 1) / tb, tb, (size_t)N * sizeof(float), stream>>>(
        pre, bboxpre, tzarr, srt, bboxsrt, N);
    dim3 bgrid((HW + 255) / 256, G);
    blend1_kernel<<<bgrid, CHG, 0, stream>>>(
        (const float4*)srt, bboxsrt, pW, part, N, HW, G);
    blend2_kernel<<<(HW + tb - 1) / tb, tb, 0, stream>>>(part, bg, out, HW, G);
}

// Round 6
// 35.979 us; speedup vs baseline: 2.3668x; 2.3668x over previous
//
#include <hip/hip_runtime.h>
#include <math.h>

#define TANFOV 1.0f

// AoS gaussian record: 3 x float4
//   [0] = (tz, -0.5*conA, -conB, -0.5*conC)
//   [1] = (mx, my, op(0 if invalid), 0)
//   [2] = (c0, c1, c2, 0)
#define REC 12      // floats per gaussian
#define CHG 256     // gaussians per chunk (== blend1 block size)

// ---------------------------------------------------------------------------
// Kernel 1: per-gaussian preprocessing. frest staged through LDS so the
// stride-45 access becomes coalesced. Writes AoS record + conservative
// support bbox (x0,x1,y0,y1) + tz array + radii (to output).
// ---------------------------------------------------------------------------
#define PRE_TB 256

__global__ void preprocess_kernel(
    const float* __restrict__ xyz, const float* __restrict__ scaling,
    const float* __restrict__ rotation, const float* __restrict__ opacity,
    const float* __restrict__ fdc, const float* __restrict__ frest,
    const float* __restrict__ vm, const float* __restrict__ pm,
    const float* __restrict__ campos,
    const int* __restrict__ pH, const int* __restrict__ pW,
    float* __restrict__ pre, float4* __restrict__ bboxpre,
    float* __restrict__ tzarr, float* __restrict__ radii_out, int N)
{
    __shared__ float s_fr[PRE_TB * 45];
    int i0 = blockIdx.x * PRE_TB;
    int cnt = N - i0; if (cnt > PRE_TB) cnt = PRE_TB;
    for (int t = threadIdx.x; t < cnt * 45; t += PRE_TB)
        s_fr[t] = frest[(size_t)i0 * 45 + t];
    __syncthreads();

    int i = i0 + threadIdx.x;
    if (i >= N) return;
    float H = (float)*pH, W = (float)*pW;

    float px_ = xyz[i*3+0], py_ = xyz[i*3+1], pz_ = xyz[i*3+2];
    float s0 = expf(scaling[i*3+0]), s1 = expf(scaling[i*3+1]), s2 = expf(scaling[i*3+2]);
    float op = 1.f / (1.f + expf(-opacity[i]));

    float qw = rotation[i*4+0], qx = rotation[i*4+1], qy = rotation[i*4+2], qz = rotation[i*4+3];
    float qn = fmaxf(sqrtf(qw*qw + qx*qx + qy*qy + qz*qz), 1e-12f);
    qw /= qn; qx /= qn; qy /= qn; qz /= qn;

    float R00 = 1.f - 2.f*(qy*qy + qz*qz), R01 = 2.f*(qx*qy - qw*qz), R02 = 2.f*(qx*qz + qw*qy);
    float R10 = 2.f*(qx*qy + qw*qz), R11 = 1.f - 2.f*(qx*qx + qz*qz), R12 = 2.f*(qy*qz - qw*qx);
    float R20 = 2.f*(qx*qz - qw*qy), R21 = 2.f*(qy*qz + qw*qx), R22 = 1.f - 2.f*(qx*qx + qy*qy);

    float M00 = R00*s0, M01 = R01*s1, M02 = R02*s2;
    float M10 = R10*s0, M11 = R11*s1, M12 = R12*s2;
    float M20 = R20*s0, M21 = R21*s1, M22 = R22*s2;

    float S00 = M00*M00 + M01*M01 + M02*M02;
    float S01 = M00*M10 + M01*M11 + M02*M12;
    float S02 = M00*M20 + M01*M21 + M02*M22;
    float S11 = M10*M10 + M11*M11 + M12*M12;
    float S12 = M10*M20 + M11*M21 + M12*M22;
    float S22 = M20*M20 + M21*M21 + M22*M22;

    float t0 = px_*vm[0] + py_*vm[4] + pz_*vm[8]  + vm[12];
    float t1 = px_*vm[1] + py_*vm[5] + pz_*vm[9]  + vm[13];
    float tz = px_*vm[2] + py_*vm[6] + pz_*vm[10] + vm[14];

    float fx = W / (2.f * TANFOV), fy = H / (2.f * TANFOV);
    float lim = 1.3f * TANFOV;
    float tzs = (fabsf(tz) > 1e-6f) ? tz : 1e-6f;
    float txz = fminf(fmaxf(t0 / tzs, -lim), lim) * tzs;
    float tyz = fminf(fmaxf(t1 / tzs, -lim), lim) * tzs;
    float J00 = fx / tzs, J02 = -fx * txz / (tzs * tzs);
    float J11 = fy / tzs, J12 = -fy * tyz / (tzs * tzs);

    float T00 = J00*vm[0] + J02*vm[2];
    float T01 = J00*vm[4] + J02*vm[6];
    float T02 = J00*vm[8] + J02*vm[10];
    float T10 = J11*vm[1] + J12*vm[2];
    float T11 = J11*vm[5] + J12*vm[6];
    float T12 = J11*vm[9] + J12*vm[10];

    float u0 = S00*T00 + S01*T01 + S02*T02;
    float u1 = S01*T00 + S11*T01 + S12*T02;
    float u2 = S02*T00 + S12*T01 + S22*T02;
    float v0 = S00*T10 + S01*T11 + S02*T12;
    float v1 = S01*T10 + S11*T11 + S12*T12;
    float v2 = S02*T10 + S12*T11 + S22*T12;
    float a  = T00*u0 + T01*u1 + T02*u2 + 0.3f;
    float b  = T10*u0 + T11*u1 + T12*u2;
    float c  = T10*v0 + T11*v1 + T12*v2 + 0.3f;

    float det = a*c - b*b;
    bool valid = (tz > 0.2f) && (det > 0.f);
    float inv_det = 1.f / ((det > 0.f) ? det : 1.f);
    float conA = c * inv_det, conB = -b * inv_det, conC = a * inv_det;
    float mid = 0.5f * (a + c);
    float lam = mid + sqrtf(fmaxf(mid*mid - det, 0.1f));
    radii_out[i] = valid ? ceilf(3.f * sqrtf(lam)) : 0.f;

    float h0 = px_*pm[0] + py_*pm[4] + pz_*pm[8]  + pm[12];
    float h1 = px_*pm[1] + py_*pm[5] + pz_*pm[9]  + pm[13];
    float h3 = px_*pm[3] + py_*pm[7] + pz_*pm[11] + pm[15];
    float pw = 1.f / (h3 + 1e-7f);
    float mx = ((h0*pw + 1.f) * W - 1.f) * 0.5f;
    float my = ((h1*pw + 1.f) * H - 1.f) * 0.5f;

    float ddx = px_ - campos[0], ddy = py_ - campos[1], ddz = pz_ - campos[2];
    float dn = fmaxf(sqrtf(ddx*ddx + ddy*ddy + ddz*ddz), 1e-12f);
    float x = ddx/dn, y = ddy/dn, z = ddz/dn;
    float xx = x*x, yy = y*y, zz = z*z, xy = x*y, yz = y*z, xz = x*z;

    float basis[16];
    basis[0]  = 0.28209479177387814f;
    basis[1]  = -0.4886025119029199f * y;
    basis[2]  =  0.4886025119029199f * z;
    basis[3]  = -0.4886025119029199f * x;
    basis[4]  =  1.0925484305920792f * xy;
    basis[5]  = -1.0925484305920792f * yz;
    basis[6]  =  0.31539156525252005f * (2.f*zz - xx - yy);
    basis[7]  = -1.0925484305920792f * xz;
    basis[8]  =  0.5462742152960396f * (xx - yy);
    basis[9]  = -0.5900435899266435f * y * (3.f*xx - yy);
    basis[10] =  2.890611442640554f  * xy * z;
    basis[11] = -0.4570457994644658f * y * (4.f*zz - xx - yy);
    basis[12] =  0.3731763325901154f * z * (2.f*zz - 3.f*xx - 3.f*yy);
    basis[13] = -0.4570457994644658f * x * (4.f*zz - xx - yy);
    basis[14] =  1.445305721320277f  * z * (xx - yy);
    basis[15] = -0.5900435899266435f * x * (xx - 3.f*yy);

    const float* fr = &s_fr[threadIdx.x * 45];
    float col[3];
    #pragma unroll
    for (int ch = 0; ch < 3; ++ch) {
        float r = basis[0] * fdc[i*3 + ch];
        #pragma unroll
        for (int j = 1; j < 16; ++j)
            r += basis[j] * fr[(j-1)*3 + ch];
        col[ch] = fmaxf(r + 0.5f, 0.f);
    }

    float opv = valid ? op : 0.f;
    float4* rec = (float4*)(pre + (size_t)i * REC);
    rec[0] = make_float4(tz, -0.5f*conA, -conB, -0.5f*conC);
    rec[1] = make_float4(mx, my, opv, 0.f);
    rec[2] = make_float4(col[0], col[1], col[2], 0.f);

    float4 bb;
    if (opv > 1.f/255.f) {
        float Rr = 1.01f * sqrtf(2.f * logf(255.f * opv) * lam) + 1.f;
        bb = make_float4(mx - Rr, mx + Rr, my - Rr, my + Rr);
    } else {
        bb = make_float4(1e30f, -1e30f, 1e30f, -1e30f);   // empty
    }
    bboxpre[i] = bb;
    tzarr[i] = tz;
}

// ---------------------------------------------------------------------------
// Kernel 2a: partial rank count over 128-element tz segments (stable sort).
// grid = (N/256, NJ) = 8 x 16 = 128 blocks -> enough parallelism to hide
// latency (the fused single-pass variant at 8 blocks was 60 us).
// ---------------------------------------------------------------------------
#define SEG_L 128

__global__ void sort_count_kernel(const float* __restrict__ tzarr,
                                  int* __restrict__ rankpart, int N)
{
    __shared__ float tzs[SEG_L];
    int seg = blockIdx.y;
    int base = seg * SEG_L;
    for (int t = threadIdx.x; t < SEG_L; t += blockDim.x)
        tzs[t] = tzarr[base + t];
    __syncthreads();

    int i = blockIdx.x * blockDim.x + threadIdx.x;
    if (i >= N) return;
    float key = tzarr[i];
    int cnt = 0;
    #pragma unroll 8
    for (int j = 0; j < SEG_L; j += 4) {
        float4 v = *reinterpret_cast<float4*>(&tzs[j]);
        cnt += (v.x < key) || (v.x == key && (base + j)     < i);
        cnt += (v.y < key) || (v.y == key && (base + j + 1) < i);
        cnt += (v.z < key) || (v.z == key && (base + j + 2) < i);
        cnt += (v.w < key) || (v.w == key && (base + j + 3) < i);
    }
    rankpart[seg * N + i] = cnt;
}

// ---------------------------------------------------------------------------
// Kernel 2b: sum partial ranks, scatter AoS record + bbox to sorted position.
// ---------------------------------------------------------------------------
__global__ void sort_scatter_kernel(const float* __restrict__ pre,
                                    const float4* __restrict__ bboxpre,
                                    const int* __restrict__ rankpart,
                                    float* __restrict__ srt,
                                    float4* __restrict__ bboxsrt, int N, int NJ)
{
    int i = blockIdx.x * blockDim.x + threadIdx.x;
    if (i >= N) return;
    int rank = 0;
    for (int s = 0; s < NJ; ++s) rank += rankpart[s * N + i];
    const float4* src = (const float4*)(pre + (size_t)i * REC);
    float4* dst = (float4*)(srt + (size_t)rank * REC);
    dst[0] = src[0]; dst[1] = src[1]; dst[2] = src[2];
    bboxsrt[rank] = bboxpre[i];
}

// ---------------------------------------------------------------------------
// Kernel 3: tile blend. Block = one 16x16 pixel tile x one 256-gaussian
// chunk (blockIdx.y). Phase A: each thread bbox-tests one gaussian against
// the tile (coalesced vector load), order-preserving ballot compaction into
// an LDS survivor list. Phase B: cooperative copy of survivor records to
// LDS, then per-pixel sequential blend over survivors (LDS broadcasts).
// part layout: field*(G*HW) + chunk*HW + pix; fields 0..2 color, 3 depth, 4 T
// Assumes W % 16 == 0 (true for this instance).
// ---------------------------------------------------------------------------
__global__ void blend1_kernel(const float4* __restrict__ grec,
                              const float4* __restrict__ bbox,
                              const int* __restrict__ pW,
                              float* __restrict__ part,
                              int N, int HW, int G)
{
    __shared__ int    s_cnt[4];
    __shared__ int    s_idx[CHG];
    __shared__ float4 s_rec[3 * CHG];

    int tid = threadIdx.x;
    int W = *pW;
    int tilesX = (W + 15) >> 4;
    int tileX = blockIdx.x % tilesX;
    int tileY = blockIdx.x / tilesX;
    int px = (tileX << 4) + (tid & 15);
    int py = (tileY << 4) + (tid >> 4);
    int pix = py * W + px;
    float fpx = (float)px, fpy = (float)py;
    float ftx0 = (float)(tileX << 4), ftx1 = ftx0 + 15.f;
    float fty0 = (float)(tileY << 4), fty1 = fty0 + 15.f;

    int chunk = blockIdx.y;
    int g0 = chunk * CHG;

    // ---- Phase A: cull ----
    int g = g0 + tid;
    bool hit = false;
    if (g < N) {
        float4 bb = bbox[g];                       // coalesced dwordx4
        hit = (bb.x <= ftx1) && (bb.y >= ftx0) &&
              (bb.z <= fty1) && (bb.w >= fty0);
    }
    unsigned long long m = __ballot(hit);
    int lane = tid & 63, wv = tid >> 6;
    int pos = __popcll(m & ((1ull << lane) - 1ull));
    if (lane == 0) s_cnt[wv] = __popcll(m);
    __syncthreads();
    int total = s_cnt[0] + s_cnt[1] + s_cnt[2] + s_cnt[3];
    int off = 0;
    for (int w = 0; w < wv; ++w) off += s_cnt[w];
    if (hit) s_idx[off + pos] = g;
    __syncthreads();

    // ---- Phase B: stage survivor records ----
    for (int k = tid; k < 3 * total; k += CHG) {
        int s = k / 3, e = k - 3 * s;
        s_rec[k] = grec[3 * s_idx[s] + e];
    }
    __syncthreads();

    // ---- blend over survivors (depth order preserved) ----
    float T = 1.f, c0 = 0.f, c1 = 0.f, c2 = 0.f, d = 0.f;
    for (int s = 0; s < total; ++s) {
        float4 pA = s_rec[3*s+0];   // tz, a2, b2, c2
        float4 pB = s_rec[3*s+1];   // mx, my, op, -
        float4 pC = s_rec[3*s+2];   // rgb
        float dx = fpx - pB.x, dy = fpy - pB.y;
        float power = pA.y*dx*dx + pA.w*dy*dy + pA.z*dx*dy;
        float alpha = fminf(0.99f, pB.z * __expf(fminf(power, 0.f)));
        bool keep = (power <= 0.f) && (alpha >= 1.f/255.f);
        float aeff = keep ? alpha : 0.f;
        float w = aeff * T;
        c0 = fmaf(w, pC.x, c0);
        c1 = fmaf(w, pC.y, c1);
        c2 = fmaf(w, pC.z, c2);
        d  = fmaf(w, pA.x, d);
        T  = T - aeff * T;
    }
    if (pix < HW) {
        int o = chunk * HW + pix;
        int S = G * HW;
        part[0*S+o] = c0; part[1*S+o] = c1; part[2*S+o] = c2;
        part[3*S+o] = d;  part[4*S+o] = T;
    }
}

// ---------------------------------------------------------------------------
// Kernel 4: combine chunks per pixel, write final outputs.
// out layout: color[3][HW], depth[HW], amap[HW]  (radii written by kernel 1)
// ---------------------------------------------------------------------------
__global__ void blend2_kernel(const float* __restrict__ part,
                              const float* __restrict__ bg,
                              float* __restrict__ out, int HW, int G)
{
    int pix = blockIdx.x * blockDim.x + threadIdx.x;
    if (pix >= HW) return;
    int S = G * HW;
    float T = 1.f, c0 = 0.f, c1 = 0.f, c2 = 0.f, d = 0.f;
    for (int k = 0; k < G; ++k) {
        int o = k * HW + pix;
        c0 += T * part[0*S+o];
        c1 += T * part[1*S+o];
        c2 += T * part[2*S+o];
        d  += T * part[3*S+o];
        T  *= part[4*S+o];
    }
    out[0*HW+pix] = c0 + T*bg[0];
    out[1*HW+pix] = c1 + T*bg[1];
    out[2*HW+pix] = c2 + T*bg[2];
    out[3*HW+pix] = d;
    out[4*HW+pix] = 1.f - T;
}

extern "C" void kernel_launch(void* const* d_in, const int* in_sizes, int n_in,
                              void* d_out, int out_size, void* d_ws, size_t ws_size,
                              hipStream_t stream) {
    const float* xyz      = (const float*)d_in[0];
    const float* scaling  = (const float*)d_in[1];
    const float* rotation = (const float*)d_in[2];
    const float* opacity  = (const float*)d_in[3];
    const float* fdc      = (const float*)d_in[4];
    const float* frest    = (const float*)d_in[5];
    const float* vm       = (const float*)d_in[6];
    const float* pm       = (const float*)d_in[7];
    const float* campos   = (const float*)d_in[8];
    const float* bg       = (const float*)d_in[9];
    const int*   pH       = (const int*)d_in[10];
    const int*   pW       = (const int*)d_in[11];

    int N  = in_sizes[0] / 3;
    int HW = (out_size - N) / 5;
    int G  = (N + CHG - 1) / CHG;       // 8 chunks for N=2048
    int NJ = (N + SEG_L - 1) / SEG_L;   // 16 segments

    // ws layout (floats):
    //   pre     : REC*N
    //   srt     : REC*N
    //   bboxpre : 4*N
    //   bboxsrt : 4*N
    //   tzarr   : N
    //   rankpart: NJ*N (ints)
    //   part    : 5*G*HW
    float*  ws       = (float*)d_ws;
    float*  pre      = ws;
    float*  srt      = pre + (size_t)REC * N;
    float4* bboxpre  = (float4*)(srt + (size_t)REC * N);
    float4* bboxsrt  = bboxpre + N;
    float*  tzarr    = (float*)(bboxsrt + N);
    int*    rankpart = (int*)(tzarr + N);
    float*  part     = (float*)(rankpart + (size_t)NJ * N);

    float* out   = (float*)d_out;
    float* radii = out + (size_t)5 * HW;

    int tb = 256;
    preprocess_kernel<<<(N + PRE_TB - 1) / PRE_TB, PRE_TB, 0, stream>>>(
        xyz, scaling, rotation, opacity, fdc, frest, vm, pm, campos, pH, pW,
        pre, bboxpre, tzarr, radii, N);
    dim3 cgrid((N + tb - 1) / tb, NJ);
    sort_count_kernel<<<cgrid, tb, 0, stream>>>(tzarr, rankpart, N);
    sort_scatter_kernel<<<(N + tb - 1) / tb, tb, 0, stream>>>(
        pre, bboxpre, rankpart, srt, bboxsrt, N, NJ);
    dim3 bgrid((HW + 255) / 256, G);
    blend1_kernel<<<bgrid, CHG, 0, stream>>>(
        (const float4*)srt, bboxsrt, pW, part, N, HW, G);
    blend2_kernel<<<(HW + tb - 1) / tb, tb, 0, stream>>>(part, bg, out, HW, G);
}